// Round 1
// baseline (1155.587 us; speedup 1.0000x reference)
//
#include <hip/hip_runtime.h>
#include <stdint.h>

#define T_TOK 8192
#define D_DIM 1024
#define H_DIM 4096
#define NGU   8192          // 2*H interleaved gate/up columns
#define NEXP  8
#define MAX_YT 136          // 2*T/128 + NEXP worst-case M-tiles

typedef float  f32x4  __attribute__((ext_vector_type(4)));
typedef __bf16 bf16x8 __attribute__((ext_vector_type(8)));
typedef __bf16 bf16x4 __attribute__((ext_vector_type(4)));

__device__ __forceinline__ void gl_lds16(const void* g, void* l) {
  // async global->LDS, 16B/lane; LDS dest = wave-uniform base + lane*16
  __builtin_amdgcn_global_load_lds(
      (__attribute__((address_space(1))) void*)g,
      (__attribute__((address_space(3))) void*)l, 16u, 0, 0u);
}

// ---------------- router: logits, softmax, top-2, gather lists, aux partials --
__global__ __launch_bounds__(256) void router_kernel(
    const float* __restrict__ x, const float* __restrict__ rw,
    const float* __restrict__ temp,
    int* __restrict__ rowtok, float* __restrict__ rowwt,
    int* __restrict__ cnt, float* __restrict__ imp_part,
    float* __restrict__ ent_part)
{
  const int wid  = threadIdx.x >> 6;
  const int lane = threadIdx.x & 63;
  const int t    = blockIdx.x * 4 + wid;   // one wave per token

  float acc[8];
#pragma unroll
  for (int e = 0; e < 8; e++) acc[e] = 0.f;
  const float* xr = x + (size_t)t * D_DIM;
#pragma unroll
  for (int it = 0; it < 16; it++) {
    int d = it * 64 + lane;
    float xv = xr[d];
    const float4 r0 = *(const float4*)(rw + d * 8);
    const float4 r1 = *(const float4*)(rw + d * 8 + 4);
    acc[0] += xv * r0.x; acc[1] += xv * r0.y;
    acc[2] += xv * r0.z; acc[3] += xv * r0.w;
    acc[4] += xv * r1.x; acc[5] += xv * r1.y;
    acc[6] += xv * r1.z; acc[7] += xv * r1.w;
  }
#pragma unroll
  for (int e = 0; e < 8; e++) {
    float v = acc[e];
#pragma unroll
    for (int off = 32; off > 0; off >>= 1) v += __shfl_xor(v, off, 64);
    acc[e] = v;     // all lanes now hold the full logit
  }
  float tclamp = fminf(fmaxf(temp[0], 0.1f), 5.0f);
  float invt = 1.0f / tclamp;
  float mx = -1e30f;
#pragma unroll
  for (int e = 0; e < 8; e++) { acc[e] *= invt; mx = fmaxf(mx, acc[e]); }
  float p[8]; float s = 0.f;
#pragma unroll
  for (int e = 0; e < 8; e++) { p[e] = __expf(acc[e] - mx); s += p[e]; }
  float invs = 1.0f / s;
  float ent = 0.f;
#pragma unroll
  for (int e = 0; e < 8; e++) {
    p[e] *= invs;
    ent -= p[e] * __logf(fmaxf(p[e], 1e-8f));
  }
  // top-2, ties -> lowest index (matches jax top_k)
  int i1 = 0; float w1 = p[0];
#pragma unroll
  for (int e = 1; e < 8; e++) if (p[e] > w1) { w1 = p[e]; i1 = e; }
  int i2 = (i1 == 0) ? 1 : 0; float w2 = p[i2];
#pragma unroll
  for (int e = 0; e < 8; e++) if (e != i1 && p[e] > w2) { w2 = p[e]; i2 = e; }

  __shared__ float s_imp[4][8];
  __shared__ float s_ent[4];
  if (lane == 0) {
    int pos1 = atomicAdd(&cnt[i1], 1);
    rowtok[i1 * T_TOK + pos1] = t * 2;        // hid row index = t*2 + slot
    rowwt [i1 * T_TOK + pos1] = w1;
    int pos2 = atomicAdd(&cnt[i2], 1);
    rowtok[i2 * T_TOK + pos2] = t * 2 + 1;
    rowwt [i2 * T_TOK + pos2] = w2;
#pragma unroll
    for (int e = 0; e < 8; e++) s_imp[wid][e] = p[e];
    s_ent[wid] = ent;
  }
  __syncthreads();
  if (threadIdx.x < 8) {
    int e = threadIdx.x;
    imp_part[blockIdx.x * 8 + e] =
        s_imp[0][e] + s_imp[1][e] + s_imp[2][e] + s_imp[3][e];
  } else if (threadIdx.x == 8) {
    ent_part[blockIdx.x] = s_ent[0] + s_ent[1] + s_ent[2] + s_ent[3];
  }
}

// ---------------- aux losses + GEMM tile schedule ---------------------------
__global__ __launch_bounds__(256) void aux_final_kernel(
    const float* __restrict__ imp_part, const float* __restrict__ ent_part,
    const int* __restrict__ cnt, int* __restrict__ tileoff,
    float* __restrict__ out_aux)
{
  __shared__ float simp[256];
  __shared__ float sent[256];
  int tid = threadIdx.x;
  int e = tid & 7, g = tid >> 3;
  float ia = 0.f;
  for (int b = g; b < 2048; b += 32) ia += imp_part[b * 8 + e];
  simp[tid] = ia;
  float ea = 0.f;
  for (int b = tid; b < 2048; b += 256) ea += ent_part[b];
  sent[tid] = ea;
  __syncthreads();
  if (tid == 0) {
    float imp[8] = {0,0,0,0,0,0,0,0};
    float ent = 0.f;
    for (int i = 0; i < 256; i++) { imp[i & 7] += simp[i]; ent += sent[i]; }
    float aux = 0.f;
    for (int ee = 0; ee < 8; ee++) {
      float importance = imp[ee] / 8192.0f;
      float load = (float)cnt[ee] / (8192.0f + 1e-6f);
      aux += importance * load;
    }
    out_aux[0] = aux * 8.0f * 0.01f;
    out_aux[1] = (ent / 8192.0f) * 0.01f;
    out_aux[2] = 0.f;
    int off = 0;
    for (int ee = 0; ee < 8; ee++) { tileoff[ee] = off; off += (cnt[ee] + 127) >> 7; }
    tileoff[8] = off;
  }
}

// ---------------- fp32 -> bf16 cast of x ------------------------------------
__global__ __launch_bounds__(256) void convert_x_kernel(
    const float* __restrict__ x, __bf16* __restrict__ xb)
{
  size_t i = ((size_t)blockIdx.x * 256 + threadIdx.x) * 4;
  float4 v = *(const float4*)(x + i);
  bf16x4 o;
  o[0] = (__bf16)v.x; o[1] = (__bf16)v.y; o[2] = (__bf16)v.z; o[3] = (__bf16)v.w;
  *(bf16x4*)(xb + i) = o;
}

// ---------------- Wg/Wu -> interleaved transposed bf16 BguT[e][2H][D] -------
// column map: h -> n' = (h>>4)*32 + (h&15) + (up?16:0)  (granularity-16 interleave)
__global__ __launch_bounds__(256) void transpose_gu_kernel(
    const float* __restrict__ Wg, const float* __restrict__ Wu,
    __bf16* __restrict__ BguT)
{
  int e  = blockIdx.z >> 1;
  int up = blockIdx.z & 1;
  const float* src = (up ? Wu : Wg) + (size_t)e * D_DIM * H_DIM;
  int h0 = blockIdx.x * 64, d0 = blockIdx.y * 64;
  __shared__ float tile[64][65];
  int c = threadIdx.x & 63, r4 = threadIdx.x >> 6;
#pragma unroll
  for (int i = 0; i < 16; i++) {
    int r = r4 * 16 + i;
    tile[r][c] = src[(size_t)(d0 + r) * H_DIM + h0 + c];
  }
  __syncthreads();
  __bf16* dst = BguT + (size_t)e * NGU * D_DIM;
#pragma unroll
  for (int i = 0; i < 16; i++) {
    int rr = r4 * 16 + i;
    int h = h0 + rr;
    int nrow = ((h >> 4) << 5) + (h & 15) + (up << 4);
    dst[(size_t)nrow * D_DIM + d0 + c] = (__bf16)tile[c][rr];
  }
}

// ---------------- Wd -> transposed bf16 BdT[e][D][H] ------------------------
__global__ __launch_bounds__(256) void transpose_wd_kernel(
    const float* __restrict__ Wd, __bf16* __restrict__ BdT)
{
  int e = blockIdx.z;
  const float* src = Wd + (size_t)e * H_DIM * D_DIM;   // [h][d]
  int d0 = blockIdx.x * 64, h0 = blockIdx.y * 64;
  __shared__ float tile[64][65];
  int c = threadIdx.x & 63, r4 = threadIdx.x >> 6;
#pragma unroll
  for (int i = 0; i < 16; i++) {
    int r = r4 * 16 + i;                                // r over h
    tile[r][c] = src[(size_t)(h0 + r) * D_DIM + d0 + c];
  }
  __syncthreads();
  __bf16* dst = BdT + (size_t)e * D_DIM * H_DIM;
#pragma unroll
  for (int i = 0; i < 16; i++) {
    int rr = r4 * 16 + i;                               // rr over d
    dst[(size_t)(d0 + rr) * H_DIM + h0 + c] = (__bf16)tile[c][rr];
  }
}

// ---------------- GEMM1: gathered x @ BguT[e], fused SwiGLU, scaled by we ---
// 128x128 tile, BK=64, 16x16x32 bf16 MFMA, XOR-swizzled LDS (conflict-free b128)
__global__ __launch_bounds__(256, 2) void gemm1_kernel(
    const __bf16* __restrict__ xb, const __bf16* __restrict__ BguT,
    const int* __restrict__ rowtok, const float* __restrict__ rowwt,
    const int* __restrict__ cnt, const int* __restrict__ tileoff,
    __bf16* __restrict__ hid)
{
  __shared__ __bf16 As[128 * 64];
  __shared__ __bf16 Bs[128 * 64];
  __shared__ int   s_tok[128];
  __shared__ float s_wt[128];

  int y = blockIdx.y;
  if (y >= tileoff[8]) return;
  int e = 0;
  while (y >= tileoff[e + 1]) e++;
  int m0 = (y - tileoff[e]) << 7;
  int cntE = cnt[e];
  int tid = threadIdx.x;
  if (tid < 128) {
    int m = m0 + tid;
    bool v = m < cntE;
    s_tok[tid] = v ? rowtok[e * T_TOK + m] : 0;
    s_wt [tid] = v ? rowwt [e * T_TOK + m] : 0.f;
  }
  __syncthreads();

  const int n0 = blockIdx.x << 7;
  const __bf16* Bp = BguT + (size_t)e * NGU * D_DIM;
  const int lane = tid & 63;
  const int wid = tid >> 6;
  const int wm = wid >> 1, wn = wid & 1;
  const int l15 = lane & 15, l4 = lane >> 4;

  f32x4 zero = {0.f, 0.f, 0.f, 0.f};
  f32x4 acc[4][4];
#pragma unroll
  for (int a = 0; a < 4; a++)
#pragma unroll
    for (int b = 0; b < 4; b++) acc[a][b] = zero;

  int q[4], ar[4], akc[4];
#pragma unroll
  for (int c = 0; c < 4; c++) {
    q[c]   = tid + (c << 8);
    ar[c]  = q[c] >> 3;
    akc[c] = ((q[c] & 7) ^ (ar[c] & 7)) << 3;   // XOR swizzle on global side
  }

  for (int kt = 0; kt < 16; kt++) {
    int k0 = kt << 6;
#pragma unroll
    for (int c = 0; c < 4; c++) {
      const __bf16* ga = xb + (size_t)(s_tok[ar[c]] >> 1) * D_DIM + (k0 + akc[c]);
      gl_lds16(ga, &As[q[c] << 3]);
    }
#pragma unroll
    for (int c = 0; c < 4; c++) {
      const __bf16* gb = Bp + (size_t)(n0 + ar[c]) * D_DIM + (k0 + akc[c]);
      gl_lds16(gb, &Bs[q[c] << 3]);
    }
    __syncthreads();
#pragma unroll
    for (int ks = 0; ks < 2; ks++) {
      bf16x8 af[4], bfv[4];
#pragma unroll
      for (int mi = 0; mi < 4; mi++) {
        int row = wm * 64 + mi * 16 + l15;
        int kidx = (ks * 4 + l4) ^ (row & 7);
        af[mi] = *(const bf16x8*)&As[(row * 8 + kidx) * 8];
      }
#pragma unroll
      for (int ni = 0; ni < 4; ni++) {
        int row = wn * 64 + ni * 16 + l15;
        int kidx = (ks * 4 + l4) ^ (row & 7);
        bfv[ni] = *(const bf16x8*)&Bs[(row * 8 + kidx) * 8];
      }
#pragma unroll
      for (int mi = 0; mi < 4; mi++)
#pragma unroll
        for (int ni = 0; ni < 4; ni++)
          acc[mi][ni] = __builtin_amdgcn_mfma_f32_16x16x32_bf16(
              af[mi], bfv[ni], acc[mi][ni], 0, 0, 0);
    }
    __syncthreads();
  }

  // SwiGLU epilogue: n-tile pair (even=gate, odd=up) is lane-aligned
#pragma unroll
  for (int mi = 0; mi < 4; mi++) {
#pragma unroll
    for (int p2 = 0; p2 < 2; p2++) {
      f32x4 gt = acc[mi][2 * p2];
      f32x4 up = acc[mi][2 * p2 + 1];
      int nb = n0 + wn * 64 + p2 * 32;
      int h = ((nb >> 5) << 4) + l15;
#pragma unroll
      for (int r = 0; r < 4; r++) {
        int rl = wm * 64 + mi * 16 + l4 * 4 + r;
        if (m0 + rl < cntE) {
          float u = up[r];
          float hv = (u / (1.f + __expf(-u))) * gt[r] * s_wt[rl];
          hid[(size_t)s_tok[rl] * H_DIM + h] = (__bf16)hv;
        }
      }
    }
  }
}

// ---------------- GEMM2: hid @ BdT[e], scatter atomicAdd into out -----------
__global__ __launch_bounds__(256, 2) void gemm2_kernel(
    const __bf16* __restrict__ hid, const __bf16* __restrict__ BdT,
    const int* __restrict__ rowtok, const int* __restrict__ cnt,
    const int* __restrict__ tileoff, float* __restrict__ out)
{
  __shared__ __bf16 As[128 * 64];
  __shared__ __bf16 Bs[128 * 64];
  __shared__ int s_tok[128];

  int y = blockIdx.y;
  if (y >= tileoff[8]) return;
  int e = 0;
  while (y >= tileoff[e + 1]) e++;
  int m0 = (y - tileoff[e]) << 7;
  int cntE = cnt[e];
  int tid = threadIdx.x;
  if (tid < 128) {
    int m = m0 + tid;
    s_tok[tid] = (m < cntE) ? rowtok[e * T_TOK + m] : 0;
  }
  __syncthreads();

  const int n0 = blockIdx.x << 7;
  const __bf16* Bp = BdT + (size_t)e * D_DIM * H_DIM;
  const int lane = tid & 63;
  const int wid = tid >> 6;
  const int wm = wid >> 1, wn = wid & 1;
  const int l15 = lane & 15, l4 = lane >> 4;

  f32x4 zero = {0.f, 0.f, 0.f, 0.f};
  f32x4 acc[4][4];
#pragma unroll
  for (int a = 0; a < 4; a++)
#pragma unroll
    for (int b = 0; b < 4; b++) acc[a][b] = zero;

  int q[4], ar[4], akc[4];
#pragma unroll
  for (int c = 0; c < 4; c++) {
    q[c]   = tid + (c << 8);
    ar[c]  = q[c] >> 3;
    akc[c] = ((q[c] & 7) ^ (ar[c] & 7)) << 3;
  }

  for (int kt = 0; kt < 64; kt++) {
    int k0 = kt << 6;
#pragma unroll
    for (int c = 0; c < 4; c++) {
      const __bf16* ga = hid + (size_t)s_tok[ar[c]] * H_DIM + (k0 + akc[c]);
      gl_lds16(ga, &As[q[c] << 3]);
    }
#pragma unroll
    for (int c = 0; c < 4; c++) {
      const __bf16* gb = Bp + (size_t)(n0 + ar[c]) * H_DIM + (k0 + akc[c]);
      gl_lds16(gb, &Bs[q[c] << 3]);
    }
    __syncthreads();
#pragma unroll
    for (int ks = 0; ks < 2; ks++) {
      bf16x8 af[4], bfv[4];
#pragma unroll
      for (int mi = 0; mi < 4; mi++) {
        int row = wm * 64 + mi * 16 + l15;
        int kidx = (ks * 4 + l4) ^ (row & 7);
        af[mi] = *(const bf16x8*)&As[(row * 8 + kidx) * 8];
      }
#pragma unroll
      for (int ni = 0; ni < 4; ni++) {
        int row = wn * 64 + ni * 16 + l15;
        int kidx = (ks * 4 + l4) ^ (row & 7);
        bfv[ni] = *(const bf16x8*)&Bs[(row * 8 + kidx) * 8];
      }
#pragma unroll
      for (int mi = 0; mi < 4; mi++)
#pragma unroll
        for (int ni = 0; ni < 4; ni++)
          acc[mi][ni] = __builtin_amdgcn_mfma_f32_16x16x32_bf16(
              af[mi], bfv[ni], acc[mi][ni], 0, 0, 0);
    }
    __syncthreads();
  }

#pragma unroll
  for (int mi = 0; mi < 4; mi++)
#pragma unroll
    for (int ni = 0; ni < 4; ni++) {
      int coln = n0 + wn * 64 + ni * 16 + l15;
#pragma unroll
      for (int r = 0; r < 4; r++) {
        int rl = wm * 64 + mi * 16 + l4 * 4 + r;
        if (m0 + rl < cntE)
          atomicAdd(&out[(size_t)(s_tok[rl] >> 1) * D_DIM + coln], acc[mi][ni][r]);
      }
    }
}

// ---------------- launch ----------------------------------------------------
extern "C" void kernel_launch(void* const* d_in, const int* in_sizes, int n_in,
                              void* d_out, int out_size, void* d_ws, size_t ws_size,
                              hipStream_t stream)
{
  const float* x    = (const float*)d_in[0];
  const float* rw   = (const float*)d_in[1];
  const float* temp = (const float*)d_in[2];
  const float* Wg   = (const float*)d_in[3];
  const float* Wu   = (const float*)d_in[4];
  const float* Wd   = (const float*)d_in[5];
  float* out = (float*)d_out;

  char* ws = (char*)d_ws;
  size_t off = 0;
  auto alloc = [&](size_t bytes) -> void* {
    void* p = ws + off;
    off = (off + bytes + 255) & ~(size_t)255;
    return p;
  };
  __bf16* xb     = (__bf16*)alloc((size_t)T_TOK * D_DIM * 2);
  __bf16* BguT   = (__bf16*)alloc((size_t)NEXP * NGU * D_DIM * 2);
  __bf16* BdT    = (__bf16*)alloc((size_t)NEXP * D_DIM * H_DIM * 2);
  __bf16* hid    = (__bf16*)alloc((size_t)T_TOK * 2 * H_DIM * 2);
  int*    rowtok = (int*)  alloc((size_t)NEXP * T_TOK * 4);
  float*  rowwt  = (float*)alloc((size_t)NEXP * T_TOK * 4);
  int*    cnt    = (int*)  alloc(64);
  int*    tileoff= (int*)  alloc(64);
  float*  imp_part = (float*)alloc(2048 * 8 * 4);
  float*  ent_part = (float*)alloc(2048 * 4);
  (void)ws_size; (void)n_in; (void)in_sizes;

  hipMemsetAsync(d_out, 0, (size_t)out_size * 4, stream);
  hipMemsetAsync(cnt, 0, 64, stream);

  router_kernel<<<2048, 256, 0, stream>>>(x, rw, temp, rowtok, rowwt, cnt,
                                          imp_part, ent_part);
  aux_final_kernel<<<1, 256, 0, stream>>>(imp_part, ent_part, cnt, tileoff,
                                          out + (size_t)T_TOK * D_DIM);
  convert_x_kernel<<<8192, 256, 0, stream>>>(x, xb);
  transpose_gu_kernel<<<dim3(64, 16, 16), 256, 0, stream>>>(Wg, Wu, BguT);
  transpose_wd_kernel<<<dim3(16, 64, 8), 256, 0, stream>>>(Wd, BdT);
  gemm1_kernel<<<dim3(64, MAX_YT), 256, 0, stream>>>(xb, BguT, rowtok, rowwt,
                                                     cnt, tileoff, hid);
  gemm2_kernel<<<dim3(8, MAX_YT), 256, 0, stream>>>(hid, BdT, rowtok, cnt,
                                                    tileoff, out);
}

// Round 2
// 1122.780 us; speedup vs baseline: 1.0292x; 1.0292x over previous
//
#include <hip/hip_runtime.h>
#include <stdint.h>

#define T_TOK 8192
#define D_DIM 1024
#define H_DIM 4096
#define NGU   8192          // 2*H interleaved gate/up columns
#define NEXP  8
#define MAX_YT 136          // 2*T/128 + NEXP worst-case M-tiles

typedef float  f32x4  __attribute__((ext_vector_type(4)));
typedef __bf16 bf16x8 __attribute__((ext_vector_type(8)));
typedef __bf16 bf16x4 __attribute__((ext_vector_type(4)));

__device__ __forceinline__ void gl_lds16(const void* g, void* l) {
  // async global->LDS, 16B/lane; LDS dest = wave-uniform base + lane*16
  __builtin_amdgcn_global_load_lds(
      (__attribute__((address_space(1))) void*)g,
      (__attribute__((address_space(3))) void*)l, 16u, 0, 0u);
}

// ---------------- router (+ fused x->bf16 cast) -----------------------------
__global__ __launch_bounds__(256) void router_kernel(
    const float* __restrict__ x, const float* __restrict__ rw,
    const float* __restrict__ temp, __bf16* __restrict__ xb,
    int* __restrict__ rowtok, float* __restrict__ rowwt,
    int* __restrict__ cnt, float* __restrict__ imp_part,
    float* __restrict__ ent_part)
{
  const int wid  = threadIdx.x >> 6;
  const int lane = threadIdx.x & 63;
  const int t    = blockIdx.x * 4 + wid;   // one wave per token

  float acc[8];
#pragma unroll
  for (int e = 0; e < 8; e++) acc[e] = 0.f;
  const float* xr = x + (size_t)t * D_DIM;
#pragma unroll
  for (int it = 0; it < 4; it++) {
    int d = (it * 64 + lane) * 4;
    float4 v = *(const float4*)(xr + d);
    bf16x4 o;
    o[0] = (__bf16)v.x; o[1] = (__bf16)v.y;
    o[2] = (__bf16)v.z; o[3] = (__bf16)v.w;
    *(bf16x4*)(xb + (size_t)t * D_DIM + d) = o;
    float vv[4] = {v.x, v.y, v.z, v.w};
#pragma unroll
    for (int j = 0; j < 4; j++) {
      float xv = vv[j];
      const float4 r0 = *(const float4*)(rw + (d + j) * 8);
      const float4 r1 = *(const float4*)(rw + (d + j) * 8 + 4);
      acc[0] += xv * r0.x; acc[1] += xv * r0.y;
      acc[2] += xv * r0.z; acc[3] += xv * r0.w;
      acc[4] += xv * r1.x; acc[5] += xv * r1.y;
      acc[6] += xv * r1.z; acc[7] += xv * r1.w;
    }
  }
#pragma unroll
  for (int e = 0; e < 8; e++) {
    float v = acc[e];
#pragma unroll
    for (int off = 32; off > 0; off >>= 1) v += __shfl_xor(v, off, 64);
    acc[e] = v;     // all lanes now hold the full logit
  }
  float tclamp = fminf(fmaxf(temp[0], 0.1f), 5.0f);
  float invt = 1.0f / tclamp;
  float mx = -1e30f;
#pragma unroll
  for (int e = 0; e < 8; e++) { acc[e] *= invt; mx = fmaxf(mx, acc[e]); }
  float p[8]; float s = 0.f;
#pragma unroll
  for (int e = 0; e < 8; e++) { p[e] = __expf(acc[e] - mx); s += p[e]; }
  float invs = 1.0f / s;
  float ent = 0.f;
#pragma unroll
  for (int e = 0; e < 8; e++) {
    p[e] *= invs;
    ent -= p[e] * __logf(fmaxf(p[e], 1e-8f));
  }
  // top-2, ties -> lowest index (matches jax top_k)
  int i1 = 0; float w1 = p[0];
#pragma unroll
  for (int e = 1; e < 8; e++) if (p[e] > w1) { w1 = p[e]; i1 = e; }
  int i2 = (i1 == 0) ? 1 : 0; float w2 = p[i2];
#pragma unroll
  for (int e = 0; e < 8; e++) if (e != i1 && p[e] > w2) { w2 = p[e]; i2 = e; }

  __shared__ float s_imp[4][8];
  __shared__ float s_ent[4];
  if (lane == 0) {
    int pos1 = atomicAdd(&cnt[i1], 1);
    rowtok[i1 * T_TOK + pos1] = t * 2;        // hid row index = t*2 + slot
    rowwt [i1 * T_TOK + pos1] = w1;
    int pos2 = atomicAdd(&cnt[i2], 1);
    rowtok[i2 * T_TOK + pos2] = t * 2 + 1;
    rowwt [i2 * T_TOK + pos2] = w2;
#pragma unroll
    for (int e = 0; e < 8; e++) s_imp[wid][e] = p[e];
    s_ent[wid] = ent;
  }
  __syncthreads();
  if (threadIdx.x < 8) {
    int e = threadIdx.x;
    imp_part[blockIdx.x * 8 + e] =
        s_imp[0][e] + s_imp[1][e] + s_imp[2][e] + s_imp[3][e];
  } else if (threadIdx.x == 8) {
    ent_part[blockIdx.x] = s_ent[0] + s_ent[1] + s_ent[2] + s_ent[3];
  }
}

// ---------------- aux losses + GEMM tile schedule ---------------------------
__global__ __launch_bounds__(256) void aux_final_kernel(
    const float* __restrict__ imp_part, const float* __restrict__ ent_part,
    const int* __restrict__ cnt, int* __restrict__ tileoff,
    float* __restrict__ out_aux)
{
  __shared__ float simp[256];
  __shared__ float sent[256];
  int tid = threadIdx.x;
  int e = tid & 7, g = tid >> 3;
  float ia = 0.f;
  for (int b = g; b < 2048; b += 32) ia += imp_part[b * 8 + e];
  simp[tid] = ia;
  float ea = 0.f;
  for (int b = tid; b < 2048; b += 256) ea += ent_part[b];
  sent[tid] = ea;
  __syncthreads();
  if (tid == 0) {
    float imp[8] = {0,0,0,0,0,0,0,0};
    float ent = 0.f;
    for (int i = 0; i < 256; i++) { imp[i & 7] += simp[i]; ent += sent[i]; }
    float aux = 0.f;
    for (int ee = 0; ee < 8; ee++) {
      float importance = imp[ee] / 8192.0f;
      float load = (float)cnt[ee] / (8192.0f + 1e-6f);
      aux += importance * load;
    }
    out_aux[0] = aux * 8.0f * 0.01f;
    out_aux[1] = (ent / 8192.0f) * 0.01f;
    out_aux[2] = 0.f;
    int off = 0;
    for (int ee = 0; ee < 8; ee++) { tileoff[ee] = off; off += (cnt[ee] + 127) >> 7; }
    tileoff[8] = off;
  }
}

// ---------------- fused vectorized transpose+cast of all weights ------------
// z<16: Wg/Wu (e=z>>1, up=z&1): src [D][H] fp32 -> BguT[e][n'][d] bf16,
//       n' = (h>>4)*32 + (h&15) + up*16  (granularity-16 gate/up interleave)
// z>=16: Wd (e=z-16): src [H][D] fp32 -> BdT[e][d][h] bf16 (plain transpose)
// Tile: 64 src-rows x 128 src-cols. Reads float4 (1KB/wave), writes bf16x8.
// LDS stride 129 floats: write-phase banks = (rc*8+j+hl)%32, 2-way max (free).
__global__ __launch_bounds__(256) void transpose_all_kernel(
    const float* __restrict__ Wg, const float* __restrict__ Wu,
    const float* __restrict__ Wd,
    __bf16* __restrict__ BguT, __bf16* __restrict__ BdT)
{
  __shared__ float tile[64 * 129];
  int z = blockIdx.z;
  const float* src; __bf16* dst;
  int C, Kd, r0, c0, up = 0;
  bool gu = z < 16;
  if (gu) {
    int e = z >> 1; up = z & 1;
    src = (up ? Wu : Wg) + (size_t)e * D_DIM * H_DIM;
    dst = BguT + (size_t)e * NGU * D_DIM;
    C = H_DIM; Kd = D_DIM;
    c0 = (blockIdx.x & 31) << 7;  r0 = (blockIdx.x >> 5) << 6;
  } else {
    int e = z - 16;
    src = Wd + (size_t)e * H_DIM * D_DIM;
    dst = BdT + (size_t)e * D_DIM * H_DIM;
    C = D_DIM; Kd = H_DIM;
    c0 = (blockIdx.x & 7) << 7;   r0 = (blockIdx.x >> 3) << 6;
  }
  int t = threadIdx.x;
  int cq = t & 31, rb = t >> 5;
#pragma unroll
  for (int i = 0; i < 8; i++) {
    int r = rb + 8 * i;
    float4 v = *(const float4*)(src + (size_t)(r0 + r) * C + c0 + cq * 4);
    *(float4*)&tile[r * 129 + cq * 4] = v;
  }
  __syncthreads();
#pragma unroll
  for (int i = 0; i < 4; i++) {
    int c = t + (i << 8);         // chunk id 0..1023
    int hl = c >> 3;              // dst-row local (src-col local) 0..127
    int rc = c & 7;               // 8-elem k-chunk within dst row
    int dstrow;
    if (gu) { int h = c0 + hl; dstrow = ((h >> 4) << 5) + (h & 15) + (up << 4); }
    else    { dstrow = c0 + hl; }
    bf16x8 o;
#pragma unroll
    for (int j = 0; j < 8; j++)
      o[j] = (__bf16)tile[(rc * 8 + j) * 129 + hl];
    *(bf16x8*)(dst + (size_t)dstrow * Kd + r0 + rc * 8) = o;
  }
}

// ---------------- GEMM1: gathered x @ BguT[e], fused SwiGLU, scaled by we ---
// 128x128 tile, BK=64, 16x16x32 bf16 MFMA, XOR-swizzled LDS (conflict-free b128)
__global__ __launch_bounds__(256, 2) void gemm1_kernel(
    const __bf16* __restrict__ xb, const __bf16* __restrict__ BguT,
    const int* __restrict__ rowtok, const float* __restrict__ rowwt,
    const int* __restrict__ cnt, const int* __restrict__ tileoff,
    __bf16* __restrict__ hid)
{
  __shared__ __bf16 As[128 * 64];
  __shared__ __bf16 Bs[128 * 64];
  __shared__ int   s_tok[128];
  __shared__ float s_wt[128];

  int y = blockIdx.y;
  if (y >= tileoff[8]) return;
  int e = 0;
  while (y >= tileoff[e + 1]) e++;
  int m0 = (y - tileoff[e]) << 7;
  int cntE = cnt[e];
  int tid = threadIdx.x;
  if (tid < 128) {
    int m = m0 + tid;
    bool v = m < cntE;
    s_tok[tid] = v ? rowtok[e * T_TOK + m] : 0;
    s_wt [tid] = v ? rowwt [e * T_TOK + m] : 0.f;
  }
  __syncthreads();

  const int n0 = blockIdx.x << 7;
  const __bf16* Bp = BguT + (size_t)e * NGU * D_DIM;
  const int lane = tid & 63;
  const int wid = tid >> 6;
  const int wm = wid >> 1, wn = wid & 1;
  const int l15 = lane & 15, l4 = lane >> 4;

  f32x4 zero = {0.f, 0.f, 0.f, 0.f};
  f32x4 acc[4][4];
#pragma unroll
  for (int a = 0; a < 4; a++)
#pragma unroll
    for (int b = 0; b < 4; b++) acc[a][b] = zero;

  int q[4], ar[4], akc[4];
#pragma unroll
  for (int c = 0; c < 4; c++) {
    q[c]   = tid + (c << 8);
    ar[c]  = q[c] >> 3;
    akc[c] = ((q[c] & 7) ^ (ar[c] & 7)) << 3;   // XOR swizzle on global side
  }

  for (int kt = 0; kt < 16; kt++) {
    int k0 = kt << 6;
#pragma unroll
    for (int c = 0; c < 4; c++) {
      const __bf16* ga = xb + (size_t)(s_tok[ar[c]] >> 1) * D_DIM + (k0 + akc[c]);
      gl_lds16(ga, &As[q[c] << 3]);
    }
#pragma unroll
    for (int c = 0; c < 4; c++) {
      const __bf16* gb = Bp + (size_t)(n0 + ar[c]) * D_DIM + (k0 + akc[c]);
      gl_lds16(gb, &Bs[q[c] << 3]);
    }
    __syncthreads();
#pragma unroll
    for (int ks = 0; ks < 2; ks++) {
      bf16x8 af[4], bfv[4];
#pragma unroll
      for (int mi = 0; mi < 4; mi++) {
        int row = wm * 64 + mi * 16 + l15;
        int kidx = (ks * 4 + l4) ^ (row & 7);
        af[mi] = *(const bf16x8*)&As[(row * 8 + kidx) * 8];
      }
#pragma unroll
      for (int ni = 0; ni < 4; ni++) {
        int row = wn * 64 + ni * 16 + l15;
        int kidx = (ks * 4 + l4) ^ (row & 7);
        bfv[ni] = *(const bf16x8*)&Bs[(row * 8 + kidx) * 8];
      }
#pragma unroll
      for (int mi = 0; mi < 4; mi++)
#pragma unroll
        for (int ni = 0; ni < 4; ni++)
          acc[mi][ni] = __builtin_amdgcn_mfma_f32_16x16x32_bf16(
              af[mi], bfv[ni], acc[mi][ni], 0, 0, 0);
    }
    __syncthreads();
  }

  // SwiGLU epilogue: n-tile pair (even=gate, odd=up) is lane-aligned
#pragma unroll
  for (int mi = 0; mi < 4; mi++) {
#pragma unroll
    for (int p2 = 0; p2 < 2; p2++) {
      f32x4 gt = acc[mi][2 * p2];
      f32x4 up = acc[mi][2 * p2 + 1];
      int nb = n0 + wn * 64 + p2 * 32;
      int h = ((nb >> 5) << 4) + l15;
#pragma unroll
      for (int r = 0; r < 4; r++) {
        int rl = wm * 64 + mi * 16 + l4 * 4 + r;
        if (m0 + rl < cntE) {
          float u = up[r];
          float hv = (u / (1.f + __expf(-u))) * gt[r] * s_wt[rl];
          hid[(size_t)s_tok[rl] * H_DIM + h] = (__bf16)hv;
        }
      }
    }
  }
}

// ---------------- GEMM2: hid @ BdT[e], direct store into ytmp[2T][D] --------
__global__ __launch_bounds__(256, 2) void gemm2_kernel(
    const __bf16* __restrict__ hid, const __bf16* __restrict__ BdT,
    const int* __restrict__ rowtok, const int* __restrict__ cnt,
    const int* __restrict__ tileoff, float* __restrict__ ytmp)
{
  __shared__ __bf16 As[128 * 64];
  __shared__ __bf16 Bs[128 * 64];
  __shared__ int s_tok[128];

  int y = blockIdx.y;
  if (y >= tileoff[8]) return;
  int e = 0;
  while (y >= tileoff[e + 1]) e++;
  int m0 = (y - tileoff[e]) << 7;
  int cntE = cnt[e];
  int tid = threadIdx.x;
  if (tid < 128) {
    int m = m0 + tid;
    s_tok[tid] = (m < cntE) ? rowtok[e * T_TOK + m] : 0;
  }
  __syncthreads();

  const int n0 = blockIdx.x << 7;
  const __bf16* Bp = BdT + (size_t)e * D_DIM * H_DIM;
  const int lane = tid & 63;
  const int wid = tid >> 6;
  const int wm = wid >> 1, wn = wid & 1;
  const int l15 = lane & 15, l4 = lane >> 4;

  f32x4 zero = {0.f, 0.f, 0.f, 0.f};
  f32x4 acc[4][4];
#pragma unroll
  for (int a = 0; a < 4; a++)
#pragma unroll
    for (int b = 0; b < 4; b++) acc[a][b] = zero;

  int q[4], ar[4], akc[4];
#pragma unroll
  for (int c = 0; c < 4; c++) {
    q[c]   = tid + (c << 8);
    ar[c]  = q[c] >> 3;
    akc[c] = ((q[c] & 7) ^ (ar[c] & 7)) << 3;
  }

  for (int kt = 0; kt < 64; kt++) {
    int k0 = kt << 6;
#pragma unroll
    for (int c = 0; c < 4; c++) {
      const __bf16* ga = hid + (size_t)s_tok[ar[c]] * H_DIM + (k0 + akc[c]);
      gl_lds16(ga, &As[q[c] << 3]);
    }
#pragma unroll
    for (int c = 0; c < 4; c++) {
      const __bf16* gb = Bp + (size_t)(n0 + ar[c]) * H_DIM + (k0 + akc[c]);
      gl_lds16(gb, &Bs[q[c] << 3]);
    }
    __syncthreads();
#pragma unroll
    for (int ks = 0; ks < 2; ks++) {
      bf16x8 af[4], bfv[4];
#pragma unroll
      for (int mi = 0; mi < 4; mi++) {
        int row = wm * 64 + mi * 16 + l15;
        int kidx = (ks * 4 + l4) ^ (row & 7);
        af[mi] = *(const bf16x8*)&As[(row * 8 + kidx) * 8];
      }
#pragma unroll
      for (int ni = 0; ni < 4; ni++) {
        int row = wn * 64 + ni * 16 + l15;
        int kidx = (ks * 4 + l4) ^ (row & 7);
        bfv[ni] = *(const bf16x8*)&Bs[(row * 8 + kidx) * 8];
      }
#pragma unroll
      for (int mi = 0; mi < 4; mi++)
#pragma unroll
        for (int ni = 0; ni < 4; ni++)
          acc[mi][ni] = __builtin_amdgcn_mfma_f32_16x16x32_bf16(
              af[mi], bfv[ni], acc[mi][ni], 0, 0, 0);
    }
    __syncthreads();
  }

#pragma unroll
  for (int mi = 0; mi < 4; mi++)
#pragma unroll
    for (int ni = 0; ni < 4; ni++) {
      int coln = n0 + wn * 64 + ni * 16 + l15;
#pragma unroll
      for (int r = 0; r < 4; r++) {
        int rl = wm * 64 + mi * 16 + l4 * 4 + r;
        if (m0 + rl < cntE)
          ytmp[(size_t)s_tok[rl] * D_DIM + coln] = acc[mi][ni][r];
      }
    }
}

// ---------------- combine: out[t] = ytmp[2t] + ytmp[2t+1] -------------------
__global__ __launch_bounds__(256) void combine_kernel(
    const float* __restrict__ ytmp, float* __restrict__ out)
{
  size_t i = ((size_t)blockIdx.x * 256 + threadIdx.x) * 4;
  size_t t = i >> 10;            // D=1024
  size_t col = i & 1023;
  const float4 a = *(const float4*)(ytmp + ((t * 2) << 10) + col);
  const float4 b = *(const float4*)(ytmp + ((t * 2 + 1) << 10) + col);
  float4 o = {a.x + b.x, a.y + b.y, a.z + b.z, a.w + b.w};
  *(float4*)(out + i) = o;
}

// ---------------- launch ----------------------------------------------------
extern "C" void kernel_launch(void* const* d_in, const int* in_sizes, int n_in,
                              void* d_out, int out_size, void* d_ws, size_t ws_size,
                              hipStream_t stream)
{
  const float* x    = (const float*)d_in[0];
  const float* rw   = (const float*)d_in[1];
  const float* temp = (const float*)d_in[2];
  const float* Wg   = (const float*)d_in[3];
  const float* Wu   = (const float*)d_in[4];
  const float* Wd   = (const float*)d_in[5];
  float* out = (float*)d_out;

  char* ws = (char*)d_ws;
  size_t off = 0;
  auto alloc = [&](size_t bytes) -> void* {
    void* p = ws + off;
    off = (off + bytes + 255) & ~(size_t)255;
    return p;
  };
  __bf16* xb     = (__bf16*)alloc((size_t)T_TOK * D_DIM * 2);
  __bf16* BguT   = (__bf16*)alloc((size_t)NEXP * NGU * D_DIM * 2);
  __bf16* BdT    = (__bf16*)alloc((size_t)NEXP * D_DIM * H_DIM * 2);
  __bf16* hid    = (__bf16*)alloc((size_t)T_TOK * 2 * H_DIM * 2);
  int*    rowtok = (int*)  alloc((size_t)NEXP * T_TOK * 4);
  float*  rowwt  = (float*)alloc((size_t)NEXP * T_TOK * 4);
  int*    cnt    = (int*)  alloc(64);
  int*    tileoff= (int*)  alloc(64);
  float*  imp_part = (float*)alloc(2048 * 8 * 4);
  float*  ent_part = (float*)alloc(2048 * 4);
  // ytmp (67 MB) aliases BguT (134 MB): BguT is dead after gemm1 completes,
  // gemm2 (stream-ordered after) writes ytmp, combine reads it.
  float* ytmp = (float*)BguT;
  (void)ws_size; (void)n_in; (void)in_sizes;

  hipMemsetAsync(cnt, 0, 64, stream);

  router_kernel<<<2048, 256, 0, stream>>>(x, rw, temp, xb, rowtok, rowwt, cnt,
                                          imp_part, ent_part);
  aux_final_kernel<<<1, 256, 0, stream>>>(imp_part, ent_part, cnt, tileoff,
                                          out + (size_t)T_TOK * D_DIM);
  transpose_all_kernel<<<dim3(512, 1, 24), 256, 0, stream>>>(Wg, Wu, Wd,
                                                             BguT, BdT);
  gemm1_kernel<<<dim3(64, MAX_YT), 256, 0, stream>>>(xb, BguT, rowtok, rowwt,
                                                     cnt, tileoff, hid);
  gemm2_kernel<<<dim3(8, MAX_YT), 256, 0, stream>>>(hid, BdT, rowtok, cnt,
                                                    tileoff, ytmp);
  combine_kernel<<<8192, 256, 0, stream>>>(ytmp, out);
}